// Round 12
// baseline (631.452 us; speedup 1.0000x reference)
//
#include <hip/hip_runtime.h>
#include <hip/hip_bf16.h>
#include <cstdint>
#include <type_traits>

typedef __attribute__((ext_vector_type(8))) __bf16 bf16x8;
typedef __attribute__((ext_vector_type(8))) short short8;
typedef __attribute__((ext_vector_type(4))) float f32x4;
using u16 = unsigned short;

// ---- MFMA fragment-type autodetect ----
template <typename T, typename = void> struct mfma_ok : std::false_type {};
template <typename T>
struct mfma_ok<T, std::void_t<decltype(__builtin_amdgcn_mfma_f32_16x16x32_bf16(
    std::declval<T>(), std::declval<T>(), std::declval<f32x4>(), 0, 0, 0))>>
    : std::true_type {};
using frag_t = std::conditional_t<mfma_ok<bf16x8>::value, bf16x8, short8>;
static_assert(sizeof(frag_t) == 16, "frag must be 4 VGPRs");

template <typename T>
__device__ __forceinline__ f32x4 MFMA(T a, T b, f32x4 c) {
  return __builtin_amdgcn_mfma_f32_16x16x32_bf16(a, b, c, 0, 0, 0);
}

__device__ __forceinline__ void gl_lds16(const u16* g, u16* l) {
  __builtin_amdgcn_global_load_lds(
      (const __attribute__((address_space(1))) unsigned int*)g,
      (__attribute__((address_space(3))) unsigned int*)l, 16, 0, 0);
}

__device__ __forceinline__ u16 f2bf(float v) {
  __hip_bfloat16 h = __float2bfloat16(v);
  return __builtin_bit_cast(u16, h);
}

// bijective XCD swizzle (nwg % 8 == 0 for all our grids)
__device__ __forceinline__ int xcd_swz(int wid, int nwg) {
  return (wid & 7) * (nwg >> 3) + (wid >> 3);
}

// ---------------------------------------------------------------------------
// GEMM core (r4-proven, for up/down): 256x256(virtual) tile, BK=64,
// 512 thr / 8 waves (2M x 4N), per-wave 128x64 -> acc[8][4]. 2 x 64KB dbuf.
// ---------------------------------------------------------------------------
__device__ __forceinline__ void gemm256(
    const u16* __restrict__ A, int lda,
    const u16* __restrict__ B, int ldb, int K,
    u16* lds, f32x4 (&acc)[8][4])
{
  const int t = threadIdx.x;
  const int l = t & 63;
  const int w = t >> 6;
  const int wm = w >> 2, wc = w & 3;

  const int sc = (t & 7) ^ ((t >> 3) & 7);
  const u16* gA = A + (t >> 3) * lda + sc * 8;
  const u16* gB = B + (t >> 3) * ldb + sc * 8;

  const int lr = l & 15;
  const int lk = l >> 4;
  const int lx = l & 7;
  const int pk0 = ((0 + lk) ^ lx) * 8;
  const int pk1 = ((4 + lk) ^ lx) * 8;
  const int arow0 = (wm * 128 + lr) * 64;
  const int brow0 = 16384 + (wc * 64 + lr) * 64;

  const int nt = K >> 6;

#define STAGE(buf, kt) do {                                   \
    const u16* a_ = gA + (kt) * 64;                           \
    const u16* b_ = gB + (kt) * 64;                           \
    u16* s_ = (buf);                                          \
    gl_lds16(a_,             s_ + w * 512);                   \
    gl_lds16(a_ +  64 * lda, s_ +  4096 + w * 512);           \
    gl_lds16(a_ + 128 * lda, s_ +  8192 + w * 512);           \
    gl_lds16(a_ + 192 * lda, s_ + 12288 + w * 512);           \
    gl_lds16(b_,             s_ + 16384 + w * 512);           \
    gl_lds16(b_ +  64 * ldb, s_ + 20480 + w * 512);           \
    gl_lds16(b_ + 128 * ldb, s_ + 24576 + w * 512);           \
    gl_lds16(b_ + 192 * ldb, s_ + 28672 + w * 512);           \
  } while (0)

  STAGE(lds, 0);
  asm volatile("s_waitcnt vmcnt(0)" ::: "memory");
  __builtin_amdgcn_s_barrier();

  for (int kt = 0; kt < nt; ++kt) {
    u16* cur = lds + (kt & 1) * 32768;
    u16* nxt = lds + ((kt + 1) & 1) * 32768;
    if (kt + 1 < nt) STAGE(nxt, kt + 1);
    __builtin_amdgcn_sched_barrier(0);
#pragma unroll
    for (int kf = 0; kf < 2; ++kf) {
      const int pk = kf ? pk1 : pk0;
      frag_t a[8], b[4];
#pragma unroll
      for (int fm = 0; fm < 8; ++fm)
        a[fm] = *(const frag_t*)(cur + arow0 + fm * 1024 + pk);
#pragma unroll
      for (int fn = 0; fn < 4; ++fn)
        b[fn] = *(const frag_t*)(cur + brow0 + fn * 1024 + pk);
      __builtin_amdgcn_s_setprio(1);
#pragma unroll
      for (int fn = 0; fn < 4; ++fn)
#pragma unroll
        for (int fm = 0; fm < 8; ++fm)
          acc[fm][fn] = MFMA(a[fm], b[fn], acc[fm][fn]);
      __builtin_amdgcn_s_setprio(0);
    }
    asm volatile("s_waitcnt vmcnt(0)" ::: "memory");
    __builtin_amdgcn_s_barrier();
  }
#undef STAGE
}

// ---------------------------------------------------------------------------
// Kernel 1: MERGED prep + LayerNorm, writing FRAGMENT-PACKED operands.
// Packed unit = 1KB: [group][lane 0..63][8 u16], lane l = (kchunk<<4)|row15.
// xh [mt 128][kt 0..31][g 0..7] : A-frag pack of LN(x); g = row-group
//     (rows mt*128+g*16..+15), value x[row= ..+ (l&15)][k=kt*32+(l>>4)*8+j]
// hpk[head 8][mt 128][ktl 0..3][g] : same pack of h0 cols head*128..+127
// wpk[nv 0..31][kt 0..35][g] : B-frag pack; g=wc*4+fn (fn=gate i,f,z,o),
//     vcol-> actual col cc=(nv>>1)*64+((nv&1)*2+wc)*16+(l&15);
//     k<1024 -> W_fn[cc][k], else R_fn[head=nv>>2][cc&127][k-1024]
// upc [11 tiles][256 vcols][1024] (r4 layout), dnp[1024][1408] k-padded.
// ---------------------------------------------------------------------------
__global__ __launch_bounds__(256) void prep_ln_kernel(
    const float* __restrict__ seq, const float* __restrict__ h0,
    const float* __restrict__ lnw, const float* __restrict__ lnb,
    const float* __restrict__ Wi, const float* __restrict__ Wf,
    const float* __restrict__ Wz, const float* __restrict__ Wo,
    const float* __restrict__ Ri, const float* __restrict__ Rf,
    const float* __restrict__ Rz, const float* __restrict__ Ro,
    const float* __restrict__ upw, const float* __restrict__ dnw,
    u16* __restrict__ xh, u16* __restrict__ hpk,
    u16* __restrict__ wpk, u16* __restrict__ upint, u16* __restrict__ dnp)
{
  const int t = threadIdx.x;
  if (blockIdx.x < 16384) {
    const int row = blockIdx.x;
    const float4 v = ((const float4*)(seq + (size_t)row * 1024))[t];
    float s = v.x + v.y + v.z + v.w;
    float q = v.x * v.x + v.y * v.y + v.z * v.z + v.w * v.w;
#pragma unroll
    for (int o = 32; o >= 1; o >>= 1) { s += __shfl_xor(s, o); q += __shfl_xor(q, o); }
    __shared__ float sm[8];
    const int l = t & 63, w = t >> 6;
    if (l == 0) { sm[w] = s; sm[4 + w] = q; }
    __syncthreads();
    s = sm[0] + sm[1] + sm[2] + sm[3];
    q = sm[4] + sm[5] + sm[6] + sm[7];
    const float mu = s * (1.f / 1024.f);
    const float var = q * (1.f / 1024.f) - mu * mu;
    const float rstd = rsqrtf(var + 1e-5f);
    const float4 wv = ((const float4*)lnw)[t];
    const float4 bv = ((const float4*)lnb)[t];
    ushort4 o4;
    o4.x = f2bf((v.x - mu) * rstd * wv.x + bv.x);
    o4.y = f2bf((v.y - mu) * rstd * wv.y + bv.y);
    o4.z = f2bf((v.z - mu) * rstd * wv.z + bv.z);
    o4.w = f2bf((v.w - mu) * rstd * wv.w + bv.w);
    const int k0 = t * 4;
    const int mt = row >> 7, g = (row & 127) >> 4, r15 = row & 15;
    size_t dst = ((size_t)(mt * 32 + (k0 >> 5)) * 8 + g) * 512 +
                 (((k0 & 31) >> 3) * 16 + r15) * 8 + (k0 & 7);
    *(ushort4*)(xh + dst) = o4;
    const float4 h = ((const float4*)(h0 + (size_t)row * 1024))[t];
    ushort4 h4;
    h4.x = f2bf(h.x); h4.y = f2bf(h.y); h4.z = f2bf(h.z); h4.w = f2bf(h.w);
    const int hd = k0 >> 7, kh = k0 & 127;
    dst = ((size_t)((hd * 128 + mt) * 4 + (kh >> 5)) * 8 + g) * 512 +
          (((kh & 31) >> 3) * 16 + r15) * 8 + (kh & 7);
    *(ushort4*)(hpk + dst) = h4;
    return;
  }
  const int stride = 2048 * 256;
  for (int i = (blockIdx.x - 16384) * 256 + t; i < 9043968; i += stride) {
    if (i < 4718592) {
      const int u = i >> 9, off = i & 511;
      const int l = off >> 3, j = off & 7;
      const int g = u & 7, q = u >> 3;
      const int kt = q % 36, nv = q / 36;
      const int wc = g >> 2, fn = g & 3;
      const int cc = (nv >> 1) * 64 + ((nv & 1) * 2 + wc) * 16 + (l & 15);
      const int k = kt * 32 + (l >> 4) * 8 + j;
      float v;
      if (k < 1024) {
        const float* W = (fn == 0) ? Wi : (fn == 1) ? Wf : (fn == 2) ? Wz : Wo;
        v = W[cc * 1024 + k];
      } else {
        const float* R = (fn == 0) ? Ri : (fn == 1) ? Rf : (fn == 2) ? Rz : Ro;
        v = R[(nv >> 2) * 16384 + (cc & 127) * 128 + (k - 1024)];
      }
      wpk[i] = f2bf(v);
    } else if (i < 7602176) {
      const int j = i - 4718592;
      const int vcol = j >> 10, k = j & 1023;
      const int tile = vcol >> 8, wc = (vcol >> 6) & 3;
      const int half = (vcol >> 5) & 1, c32 = vcol & 31;
      const int a = tile * 128 + wc * 32 + c32;
      upint[j] = (a < 1365) ? f2bf(upw[(half * 1365 + a) * 1024 + k]) : (u16)0;
    } else {
      const int j = i - 7602176;
      const int row = j / 1408, k = j - row * 1408;
      dnp[j] = (k < 1365) ? f2bf(dnw[row * 1365 + k]) : (u16)0;
    }
  }
}

// ---------------------------------------------------------------------------
// Kernel 2: gate GEMM — LDS-FREE, BARRIER-FREE. 256 thr / 4 waves (2Mx2N),
// tile 128 rows x 128 vcols, per-wave 64x64 -> acc[4][4]. K=1152 (W then R).
// Operands pre-packed in fragment order: each frag load is ONE coalesced
// global_load_dwordx4 at wave-uniform base + lane*16B. Register double-
// buffer (unroll 2, static set index); compiler emits counted vmcnt and
// pipelines freely — no barrier domain to convoy on. Intra-block A/B reuse
// is served by L1/L2 (~16KB tile footprint). 3 blocks/CU.
// ---------------------------------------------------------------------------
__global__ __launch_bounds__(256, 3) void gate_kernel(
    const u16* __restrict__ xh, const u16* __restrict__ hpk,
    const u16* __restrict__ wpk,
    const float* __restrict__ bi, const float* __restrict__ bfv,
    const float* __restrict__ bz, const float* __restrict__ bo,
    const float* __restrict__ c0, const float* __restrict__ n0i,
    const float* __restrict__ m0,
    float* __restrict__ oc, float* __restrict__ on,
    float* __restrict__ oh, float* __restrict__ om)
{
  const int t = threadIdx.x, l = t & 63, w = t >> 6;
  const int wm = w >> 1, wc = w & 1;
  const int wid = xcd_swz(blockIdx.x, 4096);
  const int nv = wid & 31, mt = wid >> 5;
  const int head = nv >> 2;

  // wave-uniform frag bases (u16 units); per-kt stride = 8*512 = 4096
  const u16* Abase = xh  + ((size_t)(mt * 32) * 8 + wm * 4) * 512 + l * 8;
  const u16* Hbase = hpk + ((size_t)((head * 128 + mt) * 4) * 8 + wm * 4) * 512 + l * 8;
  const u16* Bbase = wpk + ((size_t)(nv * 36) * 8 + wc * 4) * 512 + l * 8;

  f32x4 acc[4][4] = {};
  frag_t a[2][4], b[2][4];

#define LOADSET(s, kt) do {                                                \
    const u16* ap_ = ((kt) < 32) ? (Abase + (size_t)(kt) * 4096)           \
                                 : (Hbase + (size_t)((kt) - 32) * 4096);   \
    const u16* bp_ = Bbase + (size_t)(kt) * 4096;                          \
    _Pragma("unroll")                                                      \
    for (int f = 0; f < 4; ++f) {                                          \
      a[s][f] = *(const frag_t*)(ap_ + f * 512);                           \
      b[s][f] = *(const frag_t*)(bp_ + f * 512);                           \
    }                                                                      \
  } while (0)

  LOADSET(0, 0);
#pragma unroll 2
  for (int kt = 0; kt < 36; ++kt) {
    if (kt + 1 < 36) LOADSET((kt + 1) & 1, kt + 1);
    const int s = kt & 1;
#pragma unroll
    for (int fn = 0; fn < 4; ++fn)
#pragma unroll
      for (int fm = 0; fm < 4; ++fm)
        acc[fm][fn] = MFMA(a[s][fm], b[s][fn], acc[fm][fn]);
  }
#undef LOADSET

  // epilogue: gate = fn; actual col cc; sLSTM pointwise in-register
  const int lr = l & 15, lk = l >> 4;
  const int cc = (nv >> 1) * 64 + ((nv & 1) * 2 + wc) * 16 + lr;
  const float biv = bi[cc], bfvv = bfv[cc], bzv = bz[cc], bov = bo[cc];
#pragma unroll
  for (int fm = 0; fm < 4; ++fm) {
    const int rbase = mt * 128 + wm * 64 + fm * 16 + lk * 4;
#pragma unroll
    for (int r = 0; r < 4; ++r) {
      const size_t idx = (size_t)(rbase + r) * 1024 + cc;
      const float it = acc[fm][0][r] + biv;
      const float ft = acc[fm][1][r] + bfvv;
      const float zt = acc[fm][2][r] + bzv;
      const float ot = acc[fm][3][r] + bov;
      const float mp = m0[idx];
      const float mt_ = fmaxf(ft + mp, it);
      const float ie = __expf(it - mt_);
      const float fe = __expf(ft - mt_ + mp);
      const float ct = fe * c0[idx] + ie * tanhf(zt);
      const float nt = fe * n0i[idx] + ie;
      const float ht = (ct / nt) / (1.f + __expf(-ot));
      oc[idx] = ct; on[idx] = nt; oh[idx] = ht; om[idx] = mt_;
    }
  }
}

// ---------------------------------------------------------------------------
// Kernel 3: GroupNorm over heads (128 ch / group), one wave per group -> bf16
// (writes ROW-layout into the xh buffer, reused as up's A)
// ---------------------------------------------------------------------------
__global__ __launch_bounds__(256) void gn_kernel(
    const float* __restrict__ h, const float* __restrict__ gw,
    const float* __restrict__ gb, u16* __restrict__ gnb)
{
  const int t = threadIdx.x, l = t & 63, w = t >> 6;
  for (int grp = blockIdx.x * 4 + w; grp < 16384 * 8; grp += gridDim.x * 4) {
    const int b = grp >> 3, hd = grp & 7;
    const float2 v = ((const float2*)(h + b * 1024 + hd * 128))[l];
    float s = v.x + v.y, q = v.x * v.x + v.y * v.y;
#pragma unroll
    for (int o = 32; o >= 1; o >>= 1) { s += __shfl_xor(s, o); q += __shfl_xor(q, o); }
    const float mu = s * (1.f / 128.f);
    const float var = q * (1.f / 128.f) - mu * mu;
    const float rstd = rsqrtf(var + 1e-5f);
    const float2 wv = ((const float2*)(gw + hd * 128))[l];
    const float2 bv = ((const float2*)(gb + hd * 128))[l];
    ushort2 o2;
    o2.x = f2bf((v.x - mu) * rstd * wv.x + bv.x);
    o2.y = f2bf((v.y - mu) * rstd * wv.y + bv.y);
    ((ushort2*)(gnb + b * 1024 + hd * 128))[l] = o2;
  }
}

// ---------------------------------------------------------------------------
// Kernel 4: up-proj; halves interleaved so (u1,u2) pair in-wave; GELU-GLU.
// ---------------------------------------------------------------------------
__global__ __launch_bounds__(512, 2) void up_kernel(
    const u16* __restrict__ gnb, const u16* __restrict__ upint,
    const float* __restrict__ upb, u16* __restrict__ g)
{
  __shared__ __align__(16) u16 lds[65536];
  const int wid = xcd_swz(blockIdx.x, 704);
  const int vt = wid % 11, mt = wid / 11;
  const int m0r = mt * 256;
  f32x4 acc[8][4] = {};
  gemm256(gnb + (size_t)m0r * 1024, 1024, upint + vt * 262144, 1024, 1024,
          lds, acc);
  const int t = threadIdx.x, l = t & 63, w = t >> 6, wm = w >> 2, wc = w & 3;
#pragma unroll
  for (int fm = 0; fm < 8; ++fm) {
    const int rbase = m0r + wm * 128 + fm * 16 + (l >> 4) * 4;
#pragma unroll
    for (int fn = 0; fn < 2; ++fn) {
      const int a = vt * 128 + wc * 32 + fn * 16 + (l & 15);
      const float b1 = (a < 1365) ? upb[a] : 0.f;
      const float b2 = (a < 1365) ? upb[1365 + a] : 0.f;
#pragma unroll
      for (int r = 0; r < 4; ++r) {
        const float u1 = acc[fm][fn][r] + b1;
        const float u2 = acc[fm][fn + 2][r] + b2;
        const float ge = 0.5f * u2 * (1.f + erff(u2 * 0.70710678118654752f));
        g[(size_t)(rbase + r) * 1408 + a] = f2bf(u1 + ge);
      }
    }
  }
}

// ---------------------------------------------------------------------------
// Kernel 5: down-proj (K=1408, zero-padded) + bias + residual -> d_out
// ---------------------------------------------------------------------------
__global__ __launch_bounds__(512, 2) void down_kernel(
    const u16* __restrict__ g, const u16* __restrict__ dnp,
    const float* __restrict__ dnb, const float* __restrict__ seq,
    float* __restrict__ out)
{
  __shared__ __align__(16) u16 lds[65536];
  const int wid = xcd_swz(blockIdx.x, 256);
  const int nc = (wid & 3) * 256;
  const int m0r = (wid >> 2) * 256;
  f32x4 acc[8][4] = {};
  gemm256(g + (size_t)m0r * 1408, 1408, dnp + nc * 1408, 1408, 1408, lds, acc);
  const int t = threadIdx.x, l = t & 63, w = t >> 6, wm = w >> 2, wc = w & 3;
#pragma unroll
  for (int fm = 0; fm < 8; ++fm) {
    const int rbase = m0r + wm * 128 + fm * 16 + (l >> 4) * 4;
#pragma unroll
    for (int fn = 0; fn < 4; ++fn) {
      const int cc = nc + wc * 64 + fn * 16 + (l & 15);
      const float bb = dnb[cc];
#pragma unroll
      for (int r = 0; r < 4; ++r) {
        const size_t idx = (size_t)(rbase + r) * 1024 + cc;
        out[idx] = acc[fm][fn][r] + bb + seq[idx];
      }
    }
  }
}

// ---------------------------------------------------------------------------
extern "C" void kernel_launch(void* const* d_in, const int* in_sizes, int n_in,
                              void* d_out, int out_size, void* d_ws, size_t ws_size,
                              hipStream_t stream) {
  const float* seq = (const float*)d_in[0];
  const float* c0  = (const float*)d_in[1];
  const float* n0i = (const float*)d_in[2];
  const float* h0  = (const float*)d_in[3];
  const float* m0  = (const float*)d_in[4];
  const float* lnw = (const float*)d_in[5];
  const float* lnb = (const float*)d_in[6];
  const float* Wz  = (const float*)d_in[7];
  const float* bz  = (const float*)d_in[8];
  const float* Wi  = (const float*)d_in[9];
  const float* bi  = (const float*)d_in[10];
  const float* Wo  = (const float*)d_in[11];
  const float* bo  = (const float*)d_in[12];
  const float* Wf  = (const float*)d_in[13];
  const float* bf_ = (const float*)d_in[14];
  const float* Rz  = (const float*)d_in[15];
  const float* Ri  = (const float*)d_in[16];
  const float* Ro  = (const float*)d_in[17];
  const float* Rf  = (const float*)d_in[18];
  const float* gw  = (const float*)d_in[19];
  const float* gb  = (const float*)d_in[20];
  const float* upw = (const float*)d_in[21];
  const float* upb = (const float*)d_in[22];
  const float* dnw = (const float*)d_in[23];
  const float* dnb = (const float*)d_in[24];

  char* ws = (char*)d_ws;
  u16* xh  = (u16*)(ws);               // 33,554,432 B (packed A; reused by gn)
  u16* hpk = (u16*)(ws + 33554432);    // 33,554,432 B (packed h0 per head)
  u16* wpk = (u16*)(ws + 67108864);    //  9,437,184 B (packed W+R frags)
  u16* upc = (u16*)(ws + 76546048);    //  5,767,168 B
  u16* dnp = (u16*)(ws + 82313216);    //  2,883,584 B
  u16* g   = (u16*)(ws + 85196800);    // 46,137,344 B

  float* out = (float*)d_out;
  float* oc = out + 16777216;
  float* on = out + 2 * 16777216;
  float* oh = out + 3 * 16777216;
  float* om = out + 4 * 16777216;

  prep_ln_kernel<<<dim3(18432), dim3(256), 0, stream>>>(
      seq, h0, lnw, lnb, Wi, Wf, Wz, Wo, Ri, Rf, Rz, Ro, upw, dnw,
      xh, hpk, wpk, upc, dnp);
  gate_kernel<<<dim3(4096), dim3(256), 0, stream>>>(
      xh, hpk, wpk, bi, bf_, bz, bo, c0, n0i, m0, oc, on, oh, om);
  gn_kernel<<<dim3(2048), dim3(256), 0, stream>>>(oh, gw, gb, xh);
  up_kernel<<<dim3(704), dim3(512), 0, stream>>>(xh, upc, upb, g);
  down_kernel<<<dim3(256), dim3(512), 0, stream>>>(g, dnp, dnb, seq, out);
}